// Round 11
// baseline (295.046 us; speedup 1.0000x reference)
//
#include <hip/hip_runtime.h>
#include <math.h>

#define B 8
#define S 2048
#define DM 1024
#define DK 64
#define M_ROWS (B*S)

typedef short s8v __attribute__((ext_vector_type(8)));     // 8 bf16 (4 VGPR)
typedef float f4v __attribute__((ext_vector_type(4)));     // 4 fp32
typedef unsigned short us4 __attribute__((ext_vector_type(4)));

__device__ __forceinline__ unsigned short f2bf(float f) {
    union { float f; unsigned u; } v; v.f = f;
    unsigned r = v.u + 0x7fffu + ((v.u >> 16) & 1u);   // RNE
    return (unsigned short)(r >> 16);
}
__device__ __forceinline__ s8v ld8(const unsigned short* p) {
    return *(const s8v*)p;
}
__device__ __forceinline__ f4v mf16(s8v a, s8v b, f4v c) {
    return __builtin_amdgcn_mfma_f32_16x16x32_bf16(a, b, c, 0, 0, 0);
}
// async global->LDS, 16B per lane.
__device__ __forceinline__ void gload16(const unsigned short* g, unsigned short* l) {
    __builtin_amdgcn_global_load_lds(
        (const __attribute__((address_space(1))) void*)g,
        (__attribute__((address_space(3))) void*)l, 16, 0, 0);
}

// ---------------- cast x (fp32 -> bf16) ----------------
__global__ __launch_bounds__(256) void cast_x(const float* __restrict__ x,
                                              unsigned short* __restrict__ xb) {
    size_t i = ((size_t)blockIdx.x * 256 + threadIdx.x) * 4;
    float4 v = *(const float4*)(x + i);
    us4 o; o.x = f2bf(v.x); o.y = f2bf(v.y); o.z = f2bf(v.z); o.w = f2bf(v.w);
    *(us4*)(xb + i) = o;
}

// ---------------- transpose + cast Wv -> Wvt[n][k] bf16 ----------------
__global__ __launch_bounds__(256) void wv_t(const float* __restrict__ Wv,
                                            unsigned short* __restrict__ Wvt) {
    __shared__ float T[32][33];
    int t = threadIdx.x;
    int k0 = blockIdx.y * 32, n0 = blockIdx.x * 32;
    int r = t >> 3, c = (t & 7) * 4;
    float4 v = *(const float4*)(Wv + (size_t)(k0 + r) * DM + n0 + c);
    T[r][c + 0] = v.x; T[r][c + 1] = v.y; T[r][c + 2] = v.z; T[r][c + 3] = v.w;
    __syncthreads();
    us4 o;
    o.x = f2bf(T[c + 0][r]); o.y = f2bf(T[c + 1][r]);
    o.z = f2bf(T[c + 2][r]); o.w = f2bf(T[c + 3][r]);
    *(us4*)(Wvt + (size_t)(n0 + r) * DM + k0 + c) = o;
}

// ---------------- transpose + cast Wq|Wk -> Wqkt[128][1024] bf16 ----------
__global__ __launch_bounds__(256) void wqk_t(const float* __restrict__ Wq,
                                             const float* __restrict__ Wk,
                                             unsigned short* __restrict__ Wqkt) {
    __shared__ float T[32][33];
    int t = threadIdx.x;
    int k0 = blockIdx.y * 32, n0 = blockIdx.x * 32;
    const float* src = (n0 < 64) ? Wq : Wk;
    int nc = (n0 < 64) ? n0 : (n0 - 64);
    int r = t >> 3, c = (t & 7) * 4;
    float4 v = *(const float4*)(src + (size_t)(k0 + r) * DK + nc + c);
    T[r][c + 0] = v.x; T[r][c + 1] = v.y; T[r][c + 2] = v.z; T[r][c + 3] = v.w;
    __syncthreads();
    us4 o;
    o.x = f2bf(T[c + 0][r]); o.y = f2bf(T[c + 1][r]);
    o.z = f2bf(T[c + 2][r]); o.w = f2bf(T[c + 3][r]);
    *(us4*)(Wqkt + (size_t)(n0 + r) * DM + k0 + c) = o;
}

// ---------------- Q/K projection: m97-style, global_load_lds, BK=64 -------
__global__ __launch_bounds__(256) void qk_mfma(
        const unsigned short* __restrict__ xb,
        const unsigned short* __restrict__ Wqkt,
        const float* __restrict__ bq, const float* __restrict__ bk,
        unsigned short* __restrict__ Q, unsigned short* __restrict__ Ko) {
    __shared__ unsigned short XS[64 * 64];
    __shared__ unsigned short WS[128 * 64];
    int t = threadIdx.x;
    int w = t >> 6, lane = t & 63, l16 = lane & 15, quad = lane >> 4;
    int m0 = blockIdx.x * 64;
    int wm = (w >> 1) * 32, wn = (w & 1) * 64;
    f4v acc[2][4] = {};
    int srow = w * 8 + (lane >> 3);
    int scol = ((lane & 7) ^ (srow & 7)) * 8;
    int soff = w * 512 + lane * 8;
    for (int k0 = 0; k0 < DM; k0 += 64) {
        __syncthreads();
        #pragma unroll
        for (int i = 0; i < 2; ++i)
            gload16(xb + (size_t)(m0 + i * 32 + srow) * DM + k0 + scol,
                    XS + i * 2048 + soff);
        #pragma unroll
        for (int i = 0; i < 4; ++i)
            gload16(Wqkt + (size_t)(i * 32 + srow) * DM + k0 + scol,
                    WS + i * 2048 + soff);
        __syncthreads();
        #pragma unroll
        for (int ks = 0; ks < 2; ++ks) {
            s8v af[2], bf[4];
            #pragma unroll
            for (int i = 0; i < 2; ++i) {
                int r = wm + i * 16 + l16;
                af[i] = *(const s8v*)&XS[r * 64 + ((ks * 4 + quad) ^ (r & 7)) * 8];
            }
            #pragma unroll
            for (int j = 0; j < 4; ++j) {
                int r = wn + j * 16 + l16;
                bf[j] = *(const s8v*)&WS[r * 64 + ((ks * 4 + quad) ^ (r & 7)) * 8];
            }
            #pragma unroll
            for (int i = 0; i < 2; ++i)
                #pragma unroll
                for (int j = 0; j < 4; ++j)
                    acc[i][j] = mf16(af[i], bf[j], acc[i][j]);
        }
    }
    #pragma unroll
    for (int j = 0; j < 4; ++j) {
        int n = wn + j * 16 + l16;
        float bias = (n < 64) ? bq[n] : bk[n - 64];
        float scale = (n < 64) ? 0.125f : 1.0f;
        unsigned short* dst = (n < 64) ? Q : Ko;
        int nn = n & 63;
        #pragma unroll
        for (int i = 0; i < 2; ++i)
            #pragma unroll
            for (int rr = 0; rr < 4; ++rr) {
                int m = m0 + wm + i * 16 + quad * 4 + rr;
                dst[(size_t)m * DK + nn] = f2bf((acc[i][j][rr] + bias) * scale);
            }
    }
}

// ---------------- V projection: bf16 MFMA, OPERAND-SWAPPED --------------
// D = mf16(W-frag, X-frag): D rows = n (hi*4+r), D cols = m=s (l16) ->
// epilogue stores have 16 lanes on consecutive s (32B runs) instead of the
// previous 64-distinct-cache-lines-per-inst scatter.
__global__ __launch_bounds__(256) void v_proj_mfma(
        const unsigned short* __restrict__ xb,
        const unsigned short* __restrict__ Wvt,
        const float* __restrict__ bv,
        unsigned short* __restrict__ Vt) {
    __shared__ unsigned short XS[128 * 64];
    __shared__ unsigned short WS[128 * 64];
    int t = threadIdx.x;
    int w = t >> 6, lane = t & 63, l16 = lane & 15, quad = lane >> 4;
    int m0 = blockIdx.y * 128, n0 = blockIdx.x * 128;
    int wm = (w >> 1) * 64, wn = (w & 1) * 64;
    f4v acc[4][4] = {};
    int srow = w * 8 + (lane >> 3);
    int scol = ((lane & 7) ^ (srow & 7)) * 8;
    int soff = w * 512 + lane * 8;
    for (int k0 = 0; k0 < DM; k0 += 64) {
        __syncthreads();
        #pragma unroll
        for (int i = 0; i < 4; ++i) {
            gload16(xb  + (size_t)(m0 + i * 32 + srow) * DM + k0 + scol,
                    XS + i * 2048 + soff);
            gload16(Wvt + (size_t)(n0 + i * 32 + srow) * DM + k0 + scol,
                    WS + i * 2048 + soff);
        }
        __syncthreads();
        #pragma unroll
        for (int ks = 0; ks < 2; ++ks) {
            s8v af[4], bf[4];
            #pragma unroll
            for (int i = 0; i < 4; ++i) {
                int r = wm + i * 16 + l16;
                af[i] = *(const s8v*)&XS[r * 64 + ((ks * 4 + quad) ^ (r & 7)) * 8];
            }
            #pragma unroll
            for (int j = 0; j < 4; ++j) {
                int r = wn + j * 16 + l16;
                bf[j] = *(const s8v*)&WS[r * 64 + ((ks * 4 + quad) ^ (r & 7)) * 8];
            }
            #pragma unroll
            for (int i = 0; i < 4; ++i)
                #pragma unroll
                for (int j = 0; j < 4; ++j)
                    acc[i][j] = mf16(bf[j], af[i], acc[i][j]);   // swapped!
        }
    }
    int bb = m0 >> 11;
    #pragma unroll
    for (int j = 0; j < 4; ++j) {
        int nb = n0 + wn + j * 16 + quad * 4;           // n-row base (hi=quad)
        f4v bias4 = *(const f4v*)&bv[nb];
        #pragma unroll
        for (int i = 0; i < 4; ++i) {
            int s = (m0 + wm + i * 16 + l16) & (S - 1); // D col l16 = m = s
            #pragma unroll
            for (int r = 0; r < 4; ++r)
                Vt[((size_t)bb * DM + nb + r) * S + s] =
                    f2bf(acc[i][j][r] + bias4[r]);
        }
    }
}

// ---------------- MFMA flash attention v5 ----------------
// Single-barrier software pipeline (all barriers full __syncthreads):
//   loop j: { QK_j -> PS[j&1]; __syncthreads; issue V_{j+1} + K_{j+1};
//             PV_j reads PS[j&1], VS[j&1] }
// Disjointness: PS[jj] readers (PV_j) precede barrier_{j+1} which precedes
// its next writer (QK_{j+2}); VS[jj] re-writers (V_{j+2} gloads, issued
// post-barrier_{j+1}) follow all VS[jj] readers (PV_j). V loads drain at
// barrier_{j+1} => window = PV_j + QK_{j+1} (was: QK only, fully exposed).
// - 512 threads (8 waves), dm-slice 256, 1 block/CU (98.8KB LDS).
// - K direct from global (L2-hot, XCD-pinned); PS double-buffered.
__global__ __launch_bounds__(512, 2) void attn_mfma(
        const unsigned short* __restrict__ Q,   // prescaled by 0.125
        const unsigned short* __restrict__ K,
        const unsigned short* __restrict__ Vt,
        float* __restrict__ out) {
    __shared__ unsigned short PS[2][128][64];    // [par][q][j], swizzled
    __shared__ float lS[128];
    __shared__ unsigned short VS[2][256][64];    // [par][n][j], swizzled

    int t = threadIdx.x;
    int w = t >> 6, lane = t & 63;
    int l16 = lane & 15, hi = lane >> 4;
    int bid = blockIdx.x;
    int b  = bid & 7;                            // dispatch%8 -> XCD = batch
    int bx = (bid >> 3) & 3;
    int by = bid >> 5;
    int dm0 = bx * 256;
    int wn = (w & 3) * 64;                       // PV n-slice (4 groups)
    int qg = (w >> 2) * 64;                      // PV q-slice (2 groups)

    // V gload geometry: thread t covers chunk (t&7) of LDS row rep*64+(t>>3)
    int vrow = t >> 3;
    int voff = t * 8;                            // LDS elems; + rep*4096
    int gcol = ((t & 7) ^ ((t >> 3) & 7)) * 8;   // inverse-swizzled source chunk

    const unsigned short* Kb = K  + (size_t)b * S * DK;
    const unsigned short* Vb = Vt + ((size_t)b * DM + dm0) * S;
    const unsigned short* kbase = Kb + (size_t)l16 * DK + hi * 8;

    #pragma unroll 1
    for (int half = 0; half < 2; ++half) {
        int qidx = half ? (15 - by) : by;
        int q0 = qidx * 128;
        int NJ = q0 + 128;
        int qw = q0 + w * 16;                    // QK q-slice (16 rows/wave)

        // Q B-fragments (cols = q), persistent
        s8v qf[2];
        #pragma unroll
        for (int ks = 0; ks < 2; ++ks)
            qf[ks] = ld8(Q + ((size_t)b * S + qw + l16) * DK + ks * 32 + hi * 8);

        float lacc = 0.f;
        f4v acc[4][4] = {};                      // [qt][nt], 64q x 64n per wave

        // prologue: issue V_0 -> VS[0] (async), K_0 -> regs
        s8v ka[8];                               // [jt*2+ks]
        #pragma unroll
        for (int rep = 0; rep < 4; ++rep)
            gload16(Vb + (size_t)(rep * 64 + vrow) * S + gcol,
                    &VS[0][0][0] + rep * 4096 + voff);
        #pragma unroll
        for (int jt = 0; jt < 4; ++jt)
            #pragma unroll
            for (int ks = 0; ks < 2; ++ks)
                ka[jt * 2 + ks] = ld8(kbase + (size_t)(jt * 16) * DK + ks * 32);

        for (int j0 = 0; j0 < NJ; j0 += 64) {
            int jj = (j0 >> 6) & 1;
            // QK^T transposed (Sc^T = K.Q^T): 64j x 16q per wave; m=0 fixed
            #pragma unroll
            for (int jt = 0; jt < 4; ++jt) {
                f4v d = {0.f, 0.f, 0.f, 0.f};
                d = mf16(ka[jt * 2 + 0], qf[0], d);
                d = mf16(ka[jt * 2 + 1], qf[1], d);
                int qglob = qw + l16;
                int jbase = j0 + jt * 16 + hi * 4;
                float p0 = (jbase + 0 <= qglob) ? __expf(d[0]) : 0.f;
                float p1 = (jbase + 1 <= qglob) ? __expf(d[1]) : 0.f;
                float p2 = (jbase + 2 <= qglob) ? __expf(d[2]) : 0.f;
                float p3 = (jbase + 3 <= qglob) ? __expf(d[3]) : 0.f;
                lacc += (p0 + p1) + (p2 + p3);
                unsigned r0, r1;
                asm("v_cvt_pk_bf16_f32 %0, %1, %2" : "=v"(r0) : "v"(p0), "v"(p1));
                asm("v_cvt_pk_bf16_f32 %0, %1, %2" : "=v"(r1) : "v"(p2), "v"(p3));
                int prow = w * 16 + l16;
                int pc = jt * 2 + (hi >> 1);
                uint2 pk2; pk2.x = r0; pk2.y = r1;
                *(uint2*)&PS[jj][prow][((pc ^ (prow & 7)) * 8) + (hi & 1) * 4] = pk2;
            }
            __syncthreads();   // PS[jj] visible; V_j (VS[jj]) drained (full window)
            int jn = j0 + 64;
            if (jn < NJ) {
                // issue V_{j+1} -> VS[jj^1] (drains at NEXT barrier)
                #pragma unroll
                for (int rep = 0; rep < 4; ++rep)
                    gload16(Vb + (size_t)(rep * 64 + vrow) * S + jn + gcol,
                            &VS[jj ^ 1][0][0] + rep * 4096 + voff);
                // K_{j+1} -> regs (consumed next iter; compiler waits there)
                #pragma unroll
                for (int jt = 0; jt < 4; ++jt)
                    #pragma unroll
                    for (int ks = 0; ks < 2; ++ks)
                        ka[jt * 2 + ks] =
                            ld8(kbase + (size_t)(jn + jt * 16) * DK + ks * 32);
            }
            // PV: O[64q x 64n per wave] += P(64x64 slice) . V(64j x 64n slice)
            __builtin_amdgcn_s_setprio(1);
            #pragma unroll
            for (int js = 0; js < 2; ++js) {
                s8v pa[4];
                #pragma unroll
                for (int qt = 0; qt < 4; ++qt) {
                    int qr = qg + qt * 16 + l16;
                    pa[qt] = *(const s8v*)&PS[jj][qr][((js * 4 + hi) ^ (qr & 7)) * 8];
                }
                #pragma unroll
                for (int nt = 0; nt < 4; ++nt) {
                    int nr = wn + nt * 16 + l16;
                    s8v vb = *(const s8v*)&VS[jj][nr][((js * 4 + hi) ^ (nr & 7)) * 8];
                    #pragma unroll
                    for (int qt = 0; qt < 4; ++qt)
                        acc[qt][nt] = mf16(pa[qt], vb, acc[qt][nt]);
                }
            }
            __builtin_amdgcn_s_setprio(0);
            // NO end-of-iter barrier: PS dbuf + VS write/read disjointness
        }

        // denominators: lanes (l16) share q across hi -> reduce over hi
        {
            float lt = lacc;
            lt += __shfl_xor(lt, 16);
            lt += __shfl_xor(lt, 32);
            if (hi == 0) lS[w * 16 + l16] = lt;
        }
        __syncthreads();   // all PV done + lS visible

        // epilogue: normalize + store fp32
        #pragma unroll
        for (int qt = 0; qt < 4; ++qt) {
            f4v lv = *(const f4v*)&lS[qg + qt * 16 + hi * 4];
            f4v inv;
            inv[0] = 1.f / lv[0]; inv[1] = 1.f / lv[1];
            inv[2] = 1.f / lv[2]; inv[3] = 1.f / lv[3];
            size_t rbase = (size_t)b * S + q0 + qg + qt * 16 + hi * 4;
            #pragma unroll
            for (int nt = 0; nt < 4; ++nt)
                #pragma unroll
                for (int r = 0; r < 4; ++r)
                    out[(rbase + r) * DM + dm0 + wn + nt * 16 + l16] =
                        acc[qt][nt][r] * inv[r];
        }
        __syncthreads();   // protect LDS before next half's prologue
    }
}

extern "C" void kernel_launch(void* const* d_in, const int* in_sizes, int n_in,
                              void* d_out, int out_size, void* d_ws, size_t ws_size,
                              hipStream_t stream) {
    const float* x  = (const float*)d_in[0];
    const float* Wq = (const float*)d_in[1];
    const float* bq = (const float*)d_in[2];
    const float* Wk = (const float*)d_in[3];
    const float* bk = (const float*)d_in[4];
    const float* Wv = (const float*)d_in[5];
    const float* bv = (const float*)d_in[6];
    float* out = (float*)d_out;

    unsigned short* xb   = (unsigned short*)d_ws;                // 16384x1024
    unsigned short* Wvt  = xb   + (size_t)M_ROWS * DM;           // 1024x1024
    unsigned short* Qb   = Wvt  + (size_t)DM * DM;               // 16384x64
    unsigned short* Kb   = Qb   + (size_t)M_ROWS * DK;           // 16384x64
    unsigned short* Vt   = Kb   + (size_t)M_ROWS * DK;           // 8x1024x2048
    unsigned short* Wqkt = Vt   + (size_t)B * DM * S;            // 128x1024

    cast_x<<<(size_t)M_ROWS * DM / 1024, 256, 0, stream>>>(x, xb);
    wv_t<<<dim3(32, 32), 256, 0, stream>>>(Wv, Wvt);
    wqk_t<<<dim3(4, 32), 256, 0, stream>>>(Wq, Wk, Wqkt);
    qk_mfma<<<M_ROWS / 64, 256, 0, stream>>>(xb, Wqkt, bq, bk, Qb, Kb);
    v_proj_mfma<<<dim3(DM / 128, M_ROWS / 128), 256, 0, stream>>>(xb, Wvt, bv, Vt);
    attn_mfma<<<dim3(256), 512, 0, stream>>>(Qb, Kb, Vt, out);
}

// Round 13
// 276.581 us; speedup vs baseline: 1.0668x; 1.0668x over previous
//
#include <hip/hip_runtime.h>
#include <math.h>

#define B 8
#define S 2048
#define DM 1024
#define DK 64
#define M_ROWS (B*S)

typedef short s8v __attribute__((ext_vector_type(8)));     // 8 bf16 (4 VGPR)
typedef float f4v __attribute__((ext_vector_type(4)));     // 4 fp32
typedef unsigned short us4 __attribute__((ext_vector_type(4)));

__device__ __forceinline__ unsigned short f2bf(float f) {
    union { float f; unsigned u; } v; v.f = f;
    unsigned r = v.u + 0x7fffu + ((v.u >> 16) & 1u);   // RNE
    return (unsigned short)(r >> 16);
}
__device__ __forceinline__ s8v ld8(const unsigned short* p) {
    return *(const s8v*)p;
}
__device__ __forceinline__ f4v mf16(s8v a, s8v b, f4v c) {
    return __builtin_amdgcn_mfma_f32_16x16x32_bf16(a, b, c, 0, 0, 0);
}
// async global->LDS, 16B per lane.
__device__ __forceinline__ void gload16(const unsigned short* g, unsigned short* l) {
    __builtin_amdgcn_global_load_lds(
        (const __attribute__((address_space(1))) void*)g,
        (__attribute__((address_space(3))) void*)l, 16, 0, 0);
}

// ---------------- cast x (fp32 -> bf16) ----------------
__global__ __launch_bounds__(256) void cast_x(const float* __restrict__ x,
                                              unsigned short* __restrict__ xb) {
    size_t i = ((size_t)blockIdx.x * 256 + threadIdx.x) * 4;
    float4 v = *(const float4*)(x + i);
    us4 o; o.x = f2bf(v.x); o.y = f2bf(v.y); o.z = f2bf(v.z); o.w = f2bf(v.w);
    *(us4*)(xb + i) = o;
}

// ---------------- transpose + cast Wv -> Wvt[n][k] bf16 ----------------
__global__ __launch_bounds__(256) void wv_t(const float* __restrict__ Wv,
                                            unsigned short* __restrict__ Wvt) {
    __shared__ float T[32][33];
    int t = threadIdx.x;
    int k0 = blockIdx.y * 32, n0 = blockIdx.x * 32;
    int r = t >> 3, c = (t & 7) * 4;
    float4 v = *(const float4*)(Wv + (size_t)(k0 + r) * DM + n0 + c);
    T[r][c + 0] = v.x; T[r][c + 1] = v.y; T[r][c + 2] = v.z; T[r][c + 3] = v.w;
    __syncthreads();
    us4 o;
    o.x = f2bf(T[c + 0][r]); o.y = f2bf(T[c + 1][r]);
    o.z = f2bf(T[c + 2][r]); o.w = f2bf(T[c + 3][r]);
    *(us4*)(Wvt + (size_t)(n0 + r) * DM + k0 + c) = o;
}

// ---------------- transpose + cast Wq|Wk -> Wqkt[128][1024] bf16 ----------
__global__ __launch_bounds__(256) void wqk_t(const float* __restrict__ Wq,
                                             const float* __restrict__ Wk,
                                             unsigned short* __restrict__ Wqkt) {
    __shared__ float T[32][33];
    int t = threadIdx.x;
    int k0 = blockIdx.y * 32, n0 = blockIdx.x * 32;
    const float* src = (n0 < 64) ? Wq : Wk;
    int nc = (n0 < 64) ? n0 : (n0 - 64);
    int r = t >> 3, c = (t & 7) * 4;
    float4 v = *(const float4*)(src + (size_t)(k0 + r) * DK + nc + c);
    T[r][c + 0] = v.x; T[r][c + 1] = v.y; T[r][c + 2] = v.z; T[r][c + 3] = v.w;
    __syncthreads();
    us4 o;
    o.x = f2bf(T[c + 0][r]); o.y = f2bf(T[c + 1][r]);
    o.z = f2bf(T[c + 2][r]); o.w = f2bf(T[c + 3][r]);
    *(us4*)(Wqkt + (size_t)(n0 + r) * DM + k0 + c) = o;
}

// ---------------- Q/K projection: m97-style, global_load_lds, BK=64 -------
__global__ __launch_bounds__(256) void qk_mfma(
        const unsigned short* __restrict__ xb,
        const unsigned short* __restrict__ Wqkt,
        const float* __restrict__ bq, const float* __restrict__ bk,
        unsigned short* __restrict__ Q, unsigned short* __restrict__ Ko) {
    __shared__ unsigned short XS[64 * 64];
    __shared__ unsigned short WS[128 * 64];
    int t = threadIdx.x;
    int w = t >> 6, lane = t & 63, l16 = lane & 15, quad = lane >> 4;
    int m0 = blockIdx.x * 64;
    int wm = (w >> 1) * 32, wn = (w & 1) * 64;
    f4v acc[2][4] = {};
    int srow = w * 8 + (lane >> 3);
    int scol = ((lane & 7) ^ (srow & 7)) * 8;
    int soff = w * 512 + lane * 8;
    for (int k0 = 0; k0 < DM; k0 += 64) {
        __syncthreads();
        #pragma unroll
        for (int i = 0; i < 2; ++i)
            gload16(xb + (size_t)(m0 + i * 32 + srow) * DM + k0 + scol,
                    XS + i * 2048 + soff);
        #pragma unroll
        for (int i = 0; i < 4; ++i)
            gload16(Wqkt + (size_t)(i * 32 + srow) * DM + k0 + scol,
                    WS + i * 2048 + soff);
        __syncthreads();
        #pragma unroll
        for (int ks = 0; ks < 2; ++ks) {
            s8v af[2], bf[4];
            #pragma unroll
            for (int i = 0; i < 2; ++i) {
                int r = wm + i * 16 + l16;
                af[i] = *(const s8v*)&XS[r * 64 + ((ks * 4 + quad) ^ (r & 7)) * 8];
            }
            #pragma unroll
            for (int j = 0; j < 4; ++j) {
                int r = wn + j * 16 + l16;
                bf[j] = *(const s8v*)&WS[r * 64 + ((ks * 4 + quad) ^ (r & 7)) * 8];
            }
            #pragma unroll
            for (int i = 0; i < 2; ++i)
                #pragma unroll
                for (int j = 0; j < 4; ++j)
                    acc[i][j] = mf16(af[i], bf[j], acc[i][j]);
        }
    }
    #pragma unroll
    for (int j = 0; j < 4; ++j) {
        int n = wn + j * 16 + l16;
        float bias = (n < 64) ? bq[n] : bk[n - 64];
        float scale = (n < 64) ? 0.125f : 1.0f;
        unsigned short* dst = (n < 64) ? Q : Ko;
        int nn = n & 63;
        #pragma unroll
        for (int i = 0; i < 2; ++i)
            #pragma unroll
            for (int rr = 0; rr < 4; ++rr) {
                int m = m0 + wm + i * 16 + quad * 4 + rr;
                dst[(size_t)m * DK + nn] = f2bf((acc[i][j][rr] + bias) * scale);
            }
    }
}

// ---------------- V projection: bf16 MFMA, operand-swapped epilogue -------
__global__ __launch_bounds__(256) void v_proj_mfma(
        const unsigned short* __restrict__ xb,
        const unsigned short* __restrict__ Wvt,
        const float* __restrict__ bv,
        unsigned short* __restrict__ Vt) {
    __shared__ unsigned short XS[128 * 64];
    __shared__ unsigned short WS[128 * 64];
    int t = threadIdx.x;
    int w = t >> 6, lane = t & 63, l16 = lane & 15, quad = lane >> 4;
    int m0 = blockIdx.y * 128, n0 = blockIdx.x * 128;
    int wm = (w >> 1) * 64, wn = (w & 1) * 64;
    f4v acc[4][4] = {};
    int srow = w * 8 + (lane >> 3);
    int scol = ((lane & 7) ^ (srow & 7)) * 8;
    int soff = w * 512 + lane * 8;
    for (int k0 = 0; k0 < DM; k0 += 64) {
        __syncthreads();
        #pragma unroll
        for (int i = 0; i < 4; ++i) {
            gload16(xb  + (size_t)(m0 + i * 32 + srow) * DM + k0 + scol,
                    XS + i * 2048 + soff);
            gload16(Wvt + (size_t)(n0 + i * 32 + srow) * DM + k0 + scol,
                    WS + i * 2048 + soff);
        }
        __syncthreads();
        #pragma unroll
        for (int ks = 0; ks < 2; ++ks) {
            s8v af[4], bf[4];
            #pragma unroll
            for (int i = 0; i < 4; ++i) {
                int r = wm + i * 16 + l16;
                af[i] = *(const s8v*)&XS[r * 64 + ((ks * 4 + quad) ^ (r & 7)) * 8];
            }
            #pragma unroll
            for (int j = 0; j < 4; ++j) {
                int r = wn + j * 16 + l16;
                bf[j] = *(const s8v*)&WS[r * 64 + ((ks * 4 + quad) ^ (r & 7)) * 8];
            }
            #pragma unroll
            for (int i = 0; i < 4; ++i)
                #pragma unroll
                for (int j = 0; j < 4; ++j)
                    acc[i][j] = mf16(bf[j], af[i], acc[i][j]);   // swapped
        }
    }
    int bb = m0 >> 11;
    #pragma unroll
    for (int j = 0; j < 4; ++j) {
        int nb = n0 + wn + j * 16 + quad * 4;           // n-row base (hi=quad)
        f4v bias4 = *(const f4v*)&bv[nb];
        #pragma unroll
        for (int i = 0; i < 4; ++i) {
            int s = (m0 + wm + i * 16 + l16) & (S - 1); // D col l16 = m = s
            #pragma unroll
            for (int r = 0; r < 4; ++r)
                Vt[((size_t)bb * DM + nb + r) * S + s] =
                    f2bf(acc[i][j][r] + bias4[r]);
        }
    }
}

// ---------------- MFMA flash attention v6 ----------------
// v4.1 schedule (2 full __syncthreads per tile, proven deterministic) at
// HALF block size -> 2 blocks/CU TLP (the v2-measured stall-hiding regime):
// - 256 threads (4 waves), dm-slice 256, q-tile 64 (pair y,31-y: 33 tiles).
// - LDS 73,984 B (PS 8K + VS dbuf 64K) -> 2 blocks/CU; grid 512 = 2/CU.
// - K direct from global (L2-hot, XCD-pinned); softmax redundancy stays 4x.
// - Per-CU MFMA/VALU identical to v4.1; barrier drains now hidden by the
//   co-resident block instead of idling the CU.
__global__ __launch_bounds__(256, 2) void attn_mfma(
        const unsigned short* __restrict__ Q,   // prescaled by 0.125
        const unsigned short* __restrict__ K,
        const unsigned short* __restrict__ Vt,
        float* __restrict__ out) {
    __shared__ unsigned short PS[64][64];        // [q][j], swizzled
    __shared__ float lS[64];
    __shared__ unsigned short VS[2][256][64];    // [buf][n][j], swizzled, dbuf

    int t = threadIdx.x;
    int w = t >> 6, lane = t & 63;               // w in 0..3
    int l16 = lane & 15, hi = lane >> 4;
    int bid = blockIdx.x;
    int b  = bid & 7;                            // dispatch%8 -> XCD = batch
    int bx = (bid >> 3) & 3;
    int by = bid >> 5;                           // 0..15
    int dm0 = bx * 256;
    int wn = w * 64;                             // PV n-slice (4 x 64 = 256)

    // V gload: 8 reps; thread covers chunk (t&7) of LDS row rep*32 + (t>>3)
    int vrow = t >> 3;                           // 0..31
    int voff = t * 8;                            // LDS elems; + rep*2048
    int gcol = ((t & 7) ^ ((t >> 3) & 7)) * 8;   // inverse-swizzled source

    const unsigned short* Kb = K  + (size_t)b * S * DK;
    const unsigned short* Vb = Vt + ((size_t)b * DM + dm0) * S;
    const unsigned short* kbase = Kb + (size_t)l16 * DK + hi * 8;

    #pragma unroll 1
    for (int half = 0; half < 2; ++half) {
        int qidx = half ? (31 - by) : by;
        int q0 = qidx * 64;
        int NJ = q0 + 64;
        int qw = q0 + w * 16;                    // QK q-slice (16 rows/wave)

        // Q B-fragments (cols = q), persistent
        s8v qf[2];
        #pragma unroll
        for (int ks = 0; ks < 2; ++ks)
            qf[ks] = ld8(Q + ((size_t)b * S + qw + l16) * DK + ks * 32 + hi * 8);

        float lacc = 0.f;
        f4v acc[4][4] = {};                      // [qt][nt], 64q x 64n per wave

        // prologue: stage j0 = 0 (V -> LDS async, K -> regs)
        s8v ka[8];                               // [jt*2+ks]
        #pragma unroll
        for (int rep = 0; rep < 8; ++rep)
            gload16(Vb + (size_t)(rep * 32 + vrow) * S + gcol,
                    &VS[0][0][0] + rep * 2048 + voff);
        #pragma unroll
        for (int jt = 0; jt < 4; ++jt)
            #pragma unroll
            for (int ks = 0; ks < 2; ++ks)
                ka[jt * 2 + ks] = ld8(kbase + (size_t)(jt * 16) * DK + ks * 32);
        __syncthreads();

        int cur = 0;
        for (int j0 = 0; j0 < NJ; j0 += 64) {
            int jn = j0 + 64;
            bool pf = jn < NJ;
            if (pf) {
                #pragma unroll
                for (int rep = 0; rep < 8; ++rep)
                    gload16(Vb + (size_t)(rep * 32 + vrow) * S + jn + gcol,
                            &VS[cur ^ 1][0][0] + rep * 2048 + voff);
            }
            // QK^T transposed (Sc^T = K.Q^T): 64j x 16q per wave; m=0 fixed
            #pragma unroll
            for (int jt = 0; jt < 4; ++jt) {
                f4v d = {0.f, 0.f, 0.f, 0.f};
                d = mf16(ka[jt * 2 + 0], qf[0], d);
                d = mf16(ka[jt * 2 + 1], qf[1], d);
                int qglob = qw + l16;
                int jbase = j0 + jt * 16 + hi * 4;
                float p0 = (jbase + 0 <= qglob) ? __expf(d[0]) : 0.f;
                float p1 = (jbase + 1 <= qglob) ? __expf(d[1]) : 0.f;
                float p2 = (jbase + 2 <= qglob) ? __expf(d[2]) : 0.f;
                float p3 = (jbase + 3 <= qglob) ? __expf(d[3]) : 0.f;
                lacc += (p0 + p1) + (p2 + p3);
                unsigned r0, r1;
                asm("v_cvt_pk_bf16_f32 %0, %1, %2" : "=v"(r0) : "v"(p0), "v"(p1));
                asm("v_cvt_pk_bf16_f32 %0, %1, %2" : "=v"(r1) : "v"(p2), "v"(p3));
                int prow = w * 16 + l16;             // 0..63
                int pc = jt * 2 + (hi >> 1);
                uint2 pk2; pk2.x = r0; pk2.y = r1;
                *(uint2*)&PS[prow][((pc ^ (prow & 7)) * 8) + (hi & 1) * 4] = pk2;
            }
            // prefetch next K tile into regs
            if (pf) {
                #pragma unroll
                for (int jt = 0; jt < 4; ++jt)
                    #pragma unroll
                    for (int ks = 0; ks < 2; ++ks)
                        ka[jt * 2 + ks] =
                            ld8(kbase + (size_t)(jn + jt * 16) * DK + ks * 32);
            }
            __syncthreads();   // PS visible; V(this iter) + K drained
            // PV: O[64q x 64n per wave] += P(64x64) . V(64j x 64n slice)
            __builtin_amdgcn_s_setprio(1);
            #pragma unroll
            for (int js = 0; js < 2; ++js) {
                s8v pa[4];
                #pragma unroll
                for (int qt = 0; qt < 4; ++qt) {
                    int qr = qt * 16 + l16;
                    pa[qt] = *(const s8v*)&PS[qr][((js * 4 + hi) ^ (qr & 7)) * 8];
                }
                #pragma unroll
                for (int nt = 0; nt < 4; ++nt) {
                    int nr = wn + nt * 16 + l16;
                    s8v vb = *(const s8v*)&VS[cur][nr][((js * 4 + hi) ^ (nr & 7)) * 8];
                    #pragma unroll
                    for (int qt = 0; qt < 4; ++qt)
                        acc[qt][nt] = mf16(pa[qt], vb, acc[qt][nt]);
                }
            }
            __builtin_amdgcn_s_setprio(0);
            __syncthreads();   // PV reads done before next iter's writes
            cur ^= 1;
        }

        // denominators: lanes (l16) share q across hi -> reduce over hi
        {
            float lt = lacc;
            lt += __shfl_xor(lt, 16);
            lt += __shfl_xor(lt, 32);
            if (hi == 0) lS[w * 16 + l16] = lt;
        }
        __syncthreads();

        // epilogue: normalize + store fp32
        #pragma unroll
        for (int qt = 0; qt < 4; ++qt) {
            f4v lv = *(const f4v*)&lS[qt * 16 + hi * 4];
            f4v inv;
            inv[0] = 1.f / lv[0]; inv[1] = 1.f / lv[1];
            inv[2] = 1.f / lv[2]; inv[3] = 1.f / lv[3];
            size_t rbase = (size_t)b * S + q0 + qt * 16 + hi * 4;
            #pragma unroll
            for (int nt = 0; nt < 4; ++nt)
                #pragma unroll
                for (int r = 0; r < 4; ++r)
                    out[(rbase + r) * DM + dm0 + wn + nt * 16 + l16] =
                        acc[qt][nt][r] * inv[r];
        }
        __syncthreads();   // protect LDS before next half's prologue
    }
}

extern "C" void kernel_launch(void* const* d_in, const int* in_sizes, int n_in,
                              void* d_out, int out_size, void* d_ws, size_t ws_size,
                              hipStream_t stream) {
    const float* x  = (const float*)d_in[0];
    const float* Wq = (const float*)d_in[1];
    const float* bq = (const float*)d_in[2];
    const float* Wk = (const float*)d_in[3];
    const float* bk = (const float*)d_in[4];
    const float* Wv = (const float*)d_in[5];
    const float* bv = (const float*)d_in[6];
    float* out = (float*)d_out;

    unsigned short* xb   = (unsigned short*)d_ws;                // 16384x1024
    unsigned short* Wvt  = xb   + (size_t)M_ROWS * DM;           // 1024x1024
    unsigned short* Qb   = Wvt  + (size_t)DM * DM;               // 16384x64
    unsigned short* Kb   = Qb   + (size_t)M_ROWS * DK;           // 16384x64
    unsigned short* Vt   = Kb   + (size_t)M_ROWS * DK;           // 8x1024x2048
    unsigned short* Wqkt = Vt   + (size_t)B * DM * S;            // 128x1024

    cast_x<<<(size_t)M_ROWS * DM / 1024, 256, 0, stream>>>(x, xb);
    wv_t<<<dim3(32, 32), 256, 0, stream>>>(Wv, Wvt);
    wqk_t<<<dim3(4, 32), 256, 0, stream>>>(Wq, Wk, Wqkt);
    qk_mfma<<<M_ROWS / 64, 256, 0, stream>>>(xb, Wqkt, bq, bk, Qb, Kb);
    v_proj_mfma<<<dim3(DM / 128, M_ROWS / 128), 256, 0, stream>>>(xb, Wvt, bv, Vt);
    attn_mfma<<<dim3(512), 256, 0, stream>>>(Qb, Kb, Vt, out);
}